// Round 4
// baseline (535.364 us; speedup 1.0000x reference)
//
#include <hip/hip_runtime.h>
#include <stdint.h>

// KVCacheAttention: B=4, Sq=2048, Scache=6144, Skv=8192, D=1024, scale=1/8.
// Round 4: deepen the 8-phase pipeline. All 8 staging loads for tile kt+1
// issue at the top of tile kt (vmcnt(8) counted wait -> 4-phase latency
// window), phases are (m-half x kk) quadrants with bF resident per-tile and
// aF double-buffered one phase ahead. T2 swizzle (0 bank conflicts), T5
// setprio, raw s_barriers.

#define DM 1024
#define NB 4
#define SQN 2048
#define SCC 6144
#define SKV 8192
#define NSPLIT 2
#define KSP (SKV / NSPLIT)

typedef unsigned short u16;
typedef __attribute__((ext_vector_type(8))) short short8;
typedef __attribute__((ext_vector_type(4))) float f32x4;

__device__ __forceinline__ u16 f2bf(float x) {
  unsigned u = __builtin_bit_cast(unsigned, x);
  u += 0x7fffu + ((u >> 16) & 1u);  // RNE; inputs finite
  return (u16)(u >> 16);
}

__device__ __forceinline__ void gll16(const void* g, void* l) {
  __builtin_amdgcn_global_load_lds(
      (const __attribute__((address_space(1))) void*)g,
      (__attribute__((address_space(3))) void*)l, 16, 0, 0);
}

#define FENCE() asm volatile("" ::: "memory")
#define BARRIER()                      \
  do {                                 \
    FENCE();                           \
    __builtin_amdgcn_s_barrier();      \
    FENCE();                           \
  } while (0)

// ---------------- conversions ----------------
__global__ __launch_bounds__(256) void k_cvt(const float* __restrict__ in,
                                             u16* __restrict__ out, long n4) {
  long i = (long)blockIdx.x * 256 + threadIdx.x;
  long st = (long)gridDim.x * 256;
  for (; i < n4; i += st) {
    float4 v = ((const float4*)in)[i];
    ushort4 u;
    u.x = f2bf(v.x); u.y = f2bf(v.y); u.z = f2bf(v.z); u.w = f2bf(v.w);
    ((ushort4*)out)[i] = u;
  }
}

// cached_key [4][6144][1024] f32 -> K bf16 [4][8192][1024] rows 0..6143
__global__ __launch_bounds__(256) void k_cvt_ck(const float* __restrict__ in,
                                                u16* __restrict__ out) {
  const long n4 = (long)NB * SCC * DM / 4;
  long i = (long)blockIdx.x * 256 + threadIdx.x;
  long st = (long)gridDim.x * 256;
  for (; i < n4; i += st) {
    float4 v = ((const float4*)in)[i];
    ushort4 u;
    u.x = f2bf(v.x); u.y = f2bf(v.y); u.z = f2bf(v.z); u.w = f2bf(v.w);
    long e = i * 4;
    int b = (int)(e / ((long)SCC * DM));
    long rem = e - (long)b * SCC * DM;
    *(ushort4*)(out + (long)b * SKV * DM + rem) = u;
  }
}

// ---------------- V^T builder ----------------
__global__ __launch_bounds__(256) void k_build_vt(const float* __restrict__ cv,
                                                  const u16* __restrict__ vtmp,
                                                  u16* __restrict__ VT) {
  __shared__ u16 t[64][65];
  const int kv0 = blockIdx.x * 64;
  const int d0 = blockIdx.y * 64;
  const int b = blockIdx.z;
  const int c = threadIdx.x & 63;
  const int r4 = threadIdx.x >> 6;
#pragma unroll
  for (int p = 0; p < 16; ++p) {
    int kr = p * 4 + r4;
    int kv = kv0 + kr;
    int d = d0 + c;
    u16 u;
    if (kv < SCC)
      u = f2bf(cv[((long)b * SCC + kv) * DM + d]);
    else
      u = vtmp[((long)b * SQN + (kv - SCC)) * DM + d];
    t[kr][c] = u;
  }
  __syncthreads();
#pragma unroll
  for (int p = 0; p < 16; ++p) {
    int dr = p * 4 + r4;
    VT[((long)b * DM + d0 + dr) * SKV + kv0 + c] = t[c][dr];
  }
}

// ---------------- 256x256xBK64 8-wave deep-pipelined NT GEMM ----------------
// 512 thr = 8 waves (2M x 4N); per-wave out 128x64; BK=64 (2 kk-slices).
// LDS 128 KiB: A[2][256][64] @0, B[2][256][64] @65536, XOR-swizzled
// (16B slot ^= row&7) via pre-swizzled global source (rule 21).
// Tile kt: issue all 8 gll16 for kt+1 -> buf^1; vmcnt(8) (tile kt's loads,
// issued one full tile earlier, complete); barrier; 4 phases of
// {4 aF ds_reads for next phase || 16 MFMA; barrier}. bF[2][4] per-tile.
template <int MODE>
__global__ __launch_bounds__(512, 2) void k_gemm8(
    const u16* __restrict__ A, const u16* __restrict__ B0,
    const u16* __restrict__ B1, const u16* __restrict__ B2,
    void* __restrict__ C0, void* __restrict__ C1, void* __restrict__ C2,
    float* __restrict__ sums, const float* __restrict__ bias0,
    const float* __restrict__ bias1, const float* __restrict__ bias2) {
  extern __shared__ char smem[];
  const int tid = threadIdx.x;
  const int lane = tid & 63;
  const int wv = tid >> 6;   // 0..7
  const int wr = wv >> 2;    // 0..1
  const int wc = wv & 3;     // 0..3
  const int bm = blockIdx.y * 256;
  const int bn = blockIdx.x * 256;
  const int z = blockIdx.z;

  constexpr int LD = (MODE == 2) ? SKV : DM;
  constexpr int NT = (MODE == 2) ? (KSP / 64) : (DM / 64);

  const u16 *Ab, *Bb;
  if constexpr (MODE == 0) {
    Ab = A + (long)bm * LD;
    const int which = bn >> 10;
    const u16* Bsel = which == 0 ? B0 : (which == 1 ? B1 : B2);
    Bb = Bsel + (long)(bn & 1023) * LD;
  } else if constexpr (MODE == 1) {
    Ab = A + ((long)z * SQN + bm) * LD;
    Bb = B0 + ((long)z * SKV + bn) * LD;
  } else {
    const int bb_ = z >> 1, sp = z & 1;
    Ab = A + ((long)bb_ * SQN + bm) * (long)SKV + sp * KSP;
    Bb = B0 + ((long)bb_ * DM + bn) * (long)SKV + sp * KSP;
  }

  // staging: wave wv covers rows wv*8+(lane>>3) of each 64-row round;
  // global col pre-swizzled so linear LDS write produces the swizzled tile.
  const int srow = wv * 8 + (lane >> 3);
  const int scol = ((lane & 7) ^ (lane >> 3)) * 8;
  const u16* gA = Ab + (long)srow * LD + scol;
  const u16* gB = Bb + (long)srow * LD + scol;
  u16* lA = (u16*)smem + wv * 512 + lane * 8;            // + buf*16384 + r*4096
  u16* lB = (u16*)(smem + 65536) + wv * 512 + lane * 8;

  // prologue: stage K-tile 0 into buf0
#pragma unroll
  for (int r = 0; r < 4; ++r) gll16(gA + (long)r * 64 * LD, lA + r * 4096);
#pragma unroll
  for (int r = 0; r < 4; ++r) gll16(gB + (long)r * 64 * LD, lB + r * 4096);

  f32x4 acc[8][4];
#pragma unroll
  for (int m = 0; m < 8; ++m)
#pragma unroll
    for (int n = 0; n < 4; ++n)
#pragma unroll
      for (int j = 0; j < 4; ++j) acc[m][n][j] = 0.0f;

  const int alane = lane & 15;
  const int sw = lane & 7;   // row&7 == lane&7 for all frag rows
  const int s0 = lane >> 4;  // base 16B slot

#define AFRAG(MH, M4, KK)                                                  \
  (*(const short8*)(As + (wr * 128 + ((MH)*4 + (M4)) * 16 + alane) * 128 + \
                    (((s0 + 4 * (KK)) ^ sw) * 16)))
#define BFRAG(N, KK)                                                   \
  (*(const short8*)(Bs + (wc * 64 + (N)*16 + alane) * 128 +            \
                    (((s0 + 4 * (KK)) ^ sw) * 16)))
#define MFMA16(AF, BKK, MB)                                                 \
  __builtin_amdgcn_s_setprio(1);                                            \
  _Pragma("unroll") for (int m = 0; m < 4; ++m)                             \
      _Pragma("unroll") for (int n = 0; n < 4; ++n) acc[(MB) + m][n] =      \
      __builtin_amdgcn_mfma_f32_16x16x32_bf16(AF[m], bF[BKK][n],            \
                                              acc[(MB) + m][n], 0, 0, 0);   \
  __builtin_amdgcn_s_setprio(0);

  short8 bF[2][4];
  short8 aA[4], aB[4];

  for (int kt = 0; kt < NT; ++kt) {
    const int b = kt & 1;
    const char* As = smem + b * 32768;
    const char* Bs = smem + 65536 + b * 32768;
    const int d = (b ^ 1) * 16384;
    const long knext = (kt + 1 < NT) ? (long)(kt + 1) * 64 : (long)kt * 64;
    const u16* gAn = gA + knext;
    const u16* gBn = gB + knext;

    // issue all 8 staging loads for kt+1 into buf^1 (buf^1 fully read last
    // tile; closing barrier passed). Counted wait: the 8 just-issued stay
    // in flight, tile kt's 8 (issued one tile ago) must have completed.
    gll16(gAn, lA + d);
    gll16(gAn + (long)64 * LD, lA + d + 4096);
    gll16(gAn + (long)128 * LD, lA + d + 2 * 4096);
    gll16(gAn + (long)192 * LD, lA + d + 3 * 4096);
    gll16(gBn, lB + d);
    gll16(gBn + (long)64 * LD, lB + d + 4096);
    gll16(gBn + (long)128 * LD, lB + d + 2 * 4096);
    gll16(gBn + (long)192 * LD, lB + d + 3 * 4096);
    asm volatile("s_waitcnt vmcnt(8)" ::: "memory");
    BARRIER();  // all waves' tile-kt staging visible

    // per-tile resident B fragments (both kk) + first-phase A fragments
#pragma unroll
    for (int n = 0; n < 4; ++n) bF[0][n] = BFRAG(n, 0);
#pragma unroll
    for (int n = 0; n < 4; ++n) bF[1][n] = BFRAG(n, 1);
#pragma unroll
    for (int m = 0; m < 4; ++m) aA[m] = AFRAG(0, m, 0);

    // phase 0: prefetch aB=(mh1,kk0); MFMA (mh0,kk0)
#pragma unroll
    for (int m = 0; m < 4; ++m) aB[m] = AFRAG(1, m, 0);
    MFMA16(aA, 0, 0);
    BARRIER();
    // phase 1: prefetch aA=(mh0,kk1); MFMA (mh1,kk0)
#pragma unroll
    for (int m = 0; m < 4; ++m) aA[m] = AFRAG(0, m, 1);
    MFMA16(aB, 0, 4);
    BARRIER();
    // phase 2: prefetch aB=(mh1,kk1); MFMA (mh0,kk1)
#pragma unroll
    for (int m = 0; m < 4; ++m) aB[m] = AFRAG(1, m, 1);
    MFMA16(aA, 1, 0);
    BARRIER();
    // phase 3: MFMA (mh1,kk1)
    MFMA16(aB, 1, 4);
    BARRIER();  // all reads of buf done before next tile's staging
  }
#undef AFRAG
#undef BFRAG
#undef MFMA16

  // ---------------- epilogue ----------------
  const int rsub = (lane >> 4) * 4;

  if constexpr (MODE == 0) {
    const int which = bn >> 10;
    const float* bp = which == 0 ? bias0 : (which == 1 ? bias1 : bias2);
    u16* Cq = (u16*)C0;
    u16* Ck = (u16*)C1;
    u16* Cv = (u16*)C2;
#pragma unroll
    for (int n = 0; n < 4; ++n) {
      int col = bn + wc * 64 + n * 16 + (lane & 15);
      int cc = col & 1023;
      float bb = bp[cc];
#pragma unroll
      for (int m = 0; m < 8; ++m)
#pragma unroll
        for (int j = 0; j < 4; ++j) {
          int row = bm + wr * 128 + m * 16 + rsub + j;
          u16 hv = f2bf(acc[m][n][j] + bb);
          if (which == 1) {
            int b = row >> 11, s = row & 2047;
            Ck[((long)b * SKV + SCC + s) * DM + cc] = hv;
          } else if (which == 0) {
            Cq[(long)row * DM + cc] = hv;
          } else {
            Cv[(long)row * DM + cc] = hv;
          }
        }
    }
  } else if constexpr (MODE == 1) {
    u16* Pp = (u16*)C0 + (long)z * SQN * SKV;
    float* sb = sums + z * SQN;
    const float CE = 0.18033688011112042f;  // log2(e)/8
#pragma unroll
    for (int m = 0; m < 8; ++m)
#pragma unroll
      for (int j = 0; j < 4; ++j) {
        int row = bm + wr * 128 + m * 16 + rsub + j;
        float part = 0.f;
#pragma unroll
        for (int n = 0; n < 4; ++n) {
          float e = exp2f(acc[m][n][j] * CE);
          part += e;
          Pp[(long)row * SKV + bn + wc * 64 + n * 16 + (lane & 15)] = f2bf(e);
        }
        part += __shfl_xor(part, 1);
        part += __shfl_xor(part, 2);
        part += __shfl_xor(part, 4);
        part += __shfl_xor(part, 8);
        if ((lane & 15) == 0) atomicAdd(&sb[row], part);
      }
  } else {
    float* Cp = (float*)C0 + (long)z * SQN * DM;
#pragma unroll
    for (int n = 0; n < 4; ++n) {
      int col = bn + wc * 64 + n * 16 + (lane & 15);
#pragma unroll
      for (int m = 0; m < 8; ++m)
#pragma unroll
        for (int j = 0; j < 4; ++j) {
          int row = bm + wr * 128 + m * 16 + rsub + j;
          Cp[(long)row * DM + col] = acc[m][n][j];
        }
    }
  }
}

// ---------------- reduce split-K partials + normalize ----------------
__global__ __launch_bounds__(256) void k_reduce(const float* __restrict__ Op,
                                                const float* __restrict__ sums,
                                                float* __restrict__ out) {
  const long n4 = (long)NB * SQN * DM / 4;
  long i = (long)blockIdx.x * 256 + threadIdx.x;
  if (i >= n4) return;
  long e = i * 4;
  int b = (int)(e / ((long)SQN * DM));
  long rem = e - (long)b * SQN * DM;
  int row = (int)(rem / DM);
  const long z4 = (long)SQN * DM / 4;
  long i0 = (long)(b * NSPLIT) * z4 + (rem >> 2);
  float4 a0 = ((const float4*)Op)[i0];
  float4 a1 = ((const float4*)Op)[i0 + z4];
  float inv = 1.0f / sums[b * SQN + row];
  float4 r;
  r.x = (a0.x + a1.x) * inv;
  r.y = (a0.y + a1.y) * inv;
  r.z = (a0.z + a1.z) * inv;
  r.w = (a0.w + a1.w) * inv;
  ((float4*)out)[i] = r;
}

// ---------------- launch ----------------
extern "C" void kernel_launch(void* const* d_in, const int* in_sizes, int n_in,
                              void* d_out, int out_size, void* d_ws, size_t ws_size,
                              hipStream_t stream) {
  const float* hidden = (const float*)d_in[0];
  const float* ck = (const float*)d_in[1];
  const float* cv = (const float*)d_in[2];
  const float* Wq = (const float*)d_in[3];
  const float* bq = (const float*)d_in[4];
  const float* Wk = (const float*)d_in[5];
  const float* bk = (const float*)d_in[6];
  const float* Wv = (const float*)d_in[7];
  const float* bv = (const float*)d_in[8];
  (void)in_sizes; (void)n_in; (void)out_size; (void)ws_size;

  hipFuncSetAttribute(reinterpret_cast<const void*>(&k_gemm8<0>),
                      hipFuncAttributeMaxDynamicSharedMemorySize, 131072);
  hipFuncSetAttribute(reinterpret_cast<const void*>(&k_gemm8<1>),
                      hipFuncAttributeMaxDynamicSharedMemorySize, 131072);
  hipFuncSetAttribute(reinterpret_cast<const void*>(&k_gemm8<2>),
                      hipFuncAttributeMaxDynamicSharedMemorySize, 131072);

  char* base = (char*)d_ws;
  size_t off = 0;
  auto alloc = [&](size_t bytes) {
    char* p = base + off;
    off = (off + bytes + 255) & ~(size_t)255;
    return p;
  };
  // region0 (dead before PV): Hb, weights, Qb, Kb, Vtmp. Opart aliases it.
  u16* Hb = (u16*)alloc((size_t)NB * SQN * DM * 2);
  u16* Wqb = (u16*)alloc((size_t)DM * DM * 2);
  u16* Wkb = (u16*)alloc((size_t)DM * DM * 2);
  u16* Wvb = (u16*)alloc((size_t)DM * DM * 2);
  u16* Qb = (u16*)alloc((size_t)NB * SQN * DM * 2);
  u16* Kb = (u16*)alloc((size_t)NB * SKV * DM * 2);
  u16* Vtmp = (u16*)alloc((size_t)NB * SQN * DM * 2);
  float* Opart = (float*)base;  // [NB*NSPLIT][2048][1024] f32, aliases region0
  size_t opart_bytes = (size_t)NB * NSPLIT * SQN * DM * 4;
  if (off < opart_bytes) off = (opart_bytes + 255) & ~(size_t)255;
  u16* VT = (u16*)alloc((size_t)NB * DM * SKV * 2);
  u16* P = (u16*)alloc((size_t)NB * SQN * SKV * 2);
  float* sums = (float*)alloc((size_t)NB * SQN * 4);

  // conversions
  k_cvt<<<2048, 256, 0, stream>>>(hidden, Hb, (long)NB * SQN * DM / 4);
  k_cvt<<<512, 256, 0, stream>>>(Wq, Wqb, (long)DM * DM / 4);
  k_cvt<<<512, 256, 0, stream>>>(Wk, Wkb, (long)DM * DM / 4);
  k_cvt<<<512, 256, 0, stream>>>(Wv, Wvb, (long)DM * DM / 4);
  k_cvt_ck<<<4096, 256, 0, stream>>>(ck, Kb);

  // fused QKV projection: M=8192, N=3072, K=1024
  k_gemm8<0><<<dim3(12, 32, 1), 512, 131072, stream>>>(
      Hb, Wqb, Wkb, Wvb, Qb, Kb, Vtmp, nullptr, bq, bk, bv);

  // V^T
  k_build_vt<<<dim3(SKV / 64, DM / 64, NB), 256, 0, stream>>>(cv, Vtmp, VT);

  // S = QK^T with fused exp + row sums (batched over 4)
  hipMemsetAsync(sums, 0, (size_t)NB * SQN * 4, stream);
  k_gemm8<1><<<dim3(SKV / 256, SQN / 256, NB), 512, 131072, stream>>>(
      Qb, Kb, nullptr, nullptr, P, nullptr, nullptr, sums, nullptr, nullptr, nullptr);

  // PV split-K(2): z = (batch<<1)|split
  k_gemm8<2><<<dim3(DM / 256, SQN / 256, NB * NSPLIT), 512, 131072, stream>>>(
      P, VT, nullptr, nullptr, Opart, nullptr, nullptr, nullptr, nullptr, nullptr, nullptr);

  // reduce partials + normalize
  k_reduce<<<(NB * SQN * DM / 4 + 255) / 256, 256, 0, stream>>>(
      Opart, sums, (float*)d_out);
}